// Round 5
// baseline (4604.804 us; speedup 1.0000x reference)
//
#include <hip/hip_runtime.h>
#include <hip/hip_bf16.h>

#define T_TOK 8192
#define D_DIM 1024
#define F_DIM 4096
#define NE 8

// tile geometry (BK=32 -> small LDS -> multi-block/CU)
#define BM2 256
#define BN2 128
#define BKT 32
#define KT2G (D_DIM / BKT)   // 32 gateup K-tiles
#define KTD  (F_DIM / BKT)   // 128 down K-tiles

typedef _Float16 v8h __attribute__((ext_vector_type(8)));
typedef float f32x4 __attribute__((ext_vector_type(4)));

__device__ __forceinline__ void async_lds16(void* lds, const void* g) {
    __builtin_amdgcn_global_load_lds(
        (const __attribute__((address_space(1))) void*)g,
        (__attribute__((address_space(3))) void*)lds,
        16, 0, 0);
}

// opaque LDS read with compile-time offset immediate; no alias info -> no compiler drains.
template<int OFF>
__device__ __forceinline__ v8h ds128(unsigned a) {
    v8h r;
    asm volatile("ds_read_b128 %0, %1 offset:%2" : "=v"(r) : "v"(a), "n"(OFF));
    return r;
}

#define LGKM0 asm volatile("s_waitcnt lgkmcnt(0)" ::: "memory")
#define VMCNT0 asm volatile("s_waitcnt vmcnt(0)" ::: "memory")
#define SB0 __builtin_amdgcn_sched_barrier(0)

// ---------------- router: logits -> top2 -> scatter ----------------
__global__ void router_kernel(const float* __restrict__ x,
                              const float* __restrict__ Wgate,
                              int* __restrict__ cnt,
                              int* __restrict__ rows,
                              float* __restrict__ wts) {
    int t = blockIdx.x;
    int lane = threadIdx.x;
    const float* xr = x + (size_t)t * D_DIM;
    float acc[NE];
#pragma unroll
    for (int e = 0; e < NE; ++e) acc[e] = 0.f;
#pragma unroll
    for (int i = 0; i < D_DIM / 64; ++i) {
        int d = i * 64 + lane;
        float xv = xr[d];
#pragma unroll
        for (int e = 0; e < NE; ++e) acc[e] += xv * Wgate[e * D_DIM + d];
    }
#pragma unroll
    for (int off = 32; off > 0; off >>= 1) {
#pragma unroll
        for (int e = 0; e < NE; ++e) acc[e] += __shfl_xor(acc[e], off, 64);
    }
    if (lane == 0) {
        int e0 = 0;
#pragma unroll
        for (int e = 1; e < NE; ++e) if (acc[e] > acc[e0]) e0 = e;
        int e1 = (e0 == 0) ? 1 : 0;
#pragma unroll
        for (int e = 0; e < NE; ++e) if (e != e0 && acc[e] > acc[e1]) e1 = e;
        float w0 = 1.f / (1.f + __expf(acc[e1] - acc[e0]));
        float w1 = 1.f - w0;
        int p0 = atomicAdd(&cnt[e0], 1);
        rows[e0 * T_TOK + p0] = 2 * t;
        wts[e0 * T_TOK + p0] = w0;
        int p1 = atomicAdd(&cnt[e1], 1);
        rows[e1 * T_TOK + p1] = 2 * t + 1;
        wts[e1 * T_TOK + p1] = w1;
    }
}

// ---------------- generic fp32 -> f16 convert (float4 granules) ----------------
__global__ void f32to16_kernel(const float* __restrict__ src, _Float16* __restrict__ dst) {
    int i = blockIdx.x * blockDim.x + threadIdx.x;
    float4 v = ((const float4*)src)[i];
    union { _Float16 h[4]; uint2 u; } pk;
    pk.h[0] = (_Float16)v.x; pk.h[1] = (_Float16)v.y;
    pk.h[2] = (_Float16)v.z; pk.h[3] = (_Float16)v.w;
    *(uint2*)&dst[(size_t)i * 4] = pk.u;
}

// ========== gateup: 256x128 tile, BK=32, 66KB LDS -> 2 blocks/CU ==========
// r4 post-mortem: 130KB LDS capped us at 1 block/CU; all per-tile serial segments
// (post-barrier read bunching, gathered-A staging) were fully exposed. BK=32 halves
// the double-buffer -> 2 resident blocks overlap each other's stalls (m114/m97 regime).
// Swizzle for 64B rows (4 granules): physical slot = q4 ^ ((row>>1)&3); banks
// 16*(row&1)+4*slot -> 8 quad-banks x 2 lanes = 2-way (free). Same 1-barrier/tile,
// opaque ds_read, full-tile vmcnt distance pipeline as r3.
__global__ __launch_bounds__(512, 4)
void gateup_kernel(const _Float16* __restrict__ Xh,
                   const _Float16* __restrict__ Wgh,
                   const _Float16* __restrict__ Wuh,
                   const int* __restrict__ cnt,
                   const int* __restrict__ rows,
                   const float* __restrict__ wts,
                   _Float16* __restrict__ H) {
    int e = blockIdx.z;
    int c = cnt[e];
    int row0 = blockIdx.y * BM2;
    if (row0 >= c) return;
    int col0 = blockIdx.x * BN2;

    __shared__ __align__(16) _Float16 Ab[2][BM2][BKT];   // 32 KB
    __shared__ __align__(16) _Float16 Bb[2][BM2][BKT];   // 32 KB (gate rows 0-127, up 128-255)
    __shared__ int hrow_s[BM2];
    __shared__ float w_s[BM2];

    int tid = threadIdx.x;
    int lane = tid & 63;
    int wv = tid >> 6;         // 0..7
    int wr = wv >> 2;          // 0..1  (M half: rows wr*16 + i*32)
    int wc = wv & 3;           // 0..3  (N quarter: cols wc*32)

    if (tid < BM2) {
        int p = row0 + tid;
        if (p < c) { hrow_s[tid] = rows[e * T_TOK + p]; w_s[tid] = wts[e * T_TOK + p]; }
        else       { hrow_s[tid] = -1;                  w_s[tid] = 0.f; }
    }
    __syncthreads();

    // ---- staging geometry: chunk = 16 rows x 32 cols (1KB); lane -> row rl, slot p
    int rl = lane >> 2;            // 0..15 row within chunk
    int p4 = lane & 3;             // physical granule slot
    int lg = p4 ^ ((rl >> 1) & 3); // logical granule (involution)

    // A chunks 2wv, 2wv+1 -> rows 32wv+rl, 32wv+16+rl
    int ra0 = wv * 32 + rl;
    int ra1 = ra0 + 16;
    int hA0 = hrow_s[ra0], hA1 = hrow_s[ra1];
    const _Float16* sA0 = Xh + (size_t)(hA0 >= 0 ? (hA0 >> 1) : 0) * D_DIM + lg * 8;
    const _Float16* sA1 = Xh + (size_t)(hA1 >= 0 ? (hA1 >> 1) : 0) * D_DIM + lg * 8;
    // B chunks 2wv, 2wv+1: wv<4 -> Wg rows 32wv+rl(+16); wv>=4 -> Wu rows 32(wv-4)+rl(+16)
    const _Float16* wbase = (wv < 4) ? Wgh : Wuh;
    int rb0 = (wv & 3) * 32 + rl;
    const _Float16* sB0 = wbase + ((size_t)e * F_DIM + col0 + rb0) * D_DIM + lg * 8;
    const _Float16* sB1 = wbase + ((size_t)e * F_DIM + col0 + rb0 + 16) * D_DIM + lg * 8;

    int stO = wv * 2048;   // byte offset of chunk 2wv (wave-uniform; HW adds lane*16)

    // ---- fragment-read constants (swizzled)
    int m16 = lane & 15, q4 = lane >> 4;
    int cb = ((q4 ^ ((m16 >> 1) & 3)) << 4);
    unsigned Abase = (unsigned)(size_t)(__attribute__((address_space(3))) void*)&Ab[0][0][0]
                     + (unsigned)((wr * 16 + m16) * 64 + cb);
    unsigned Bbase = (unsigned)(size_t)(__attribute__((address_space(3))) void*)&Bb[0][0][0]
                     + (unsigned)((wc * 32 + m16) * 64 + cb);

    // ---- prologue: issue stage of tile 0 into buffer 0
    {
        char* aD = (char*)Ab + stO;
        char* bD = (char*)Bb + stO;
        async_lds16(bD,        sB0);
        async_lds16(bD + 1024, sB1);
        async_lds16(aD,        sA0);
        async_lds16(aD + 1024, sA1);
    }

    f32x4 accg[8][2], accu[8][2];
#pragma unroll
    for (int i = 0; i < 8; ++i)
#pragma unroll
        for (int j = 0; j < 2; ++j) { accg[i][j] = (f32x4)0.f; accu[i][j] = (f32x4)0.f; }

    int cur = 0;
#pragma unroll 1
    for (int t = 0; t < KT2G; ++t) {
        int kn = (t + 1 < KT2G) ? (t + 1) * BKT : 0;   // clamped next-tile K offset
        int nb = cur ^ 1;

        VMCNT0;
        __builtin_amdgcn_s_barrier();
        SB0;

        {
            char* aD = (char*)Ab + nb * 16384 + stO;
            char* bD = (char*)Bb + nb * 16384 + stO;
            async_lds16(bD,        sB0 + kn);
            async_lds16(bD + 1024, sB1 + kn);
            async_lds16(aD,        sA0 + kn);
            async_lds16(aD + 1024, sA1 + kn);
        }
        SB0;

        unsigned a0 = Abase + (unsigned)(cur * 16384);
        unsigned b0 = Bbase + (unsigned)(cur * 16384);

        v8h af[4], bg[2], bu[2];

        // reads 1-8: af[0..3] (M-frags 0-3), bg, bu
        af[0] = ds128<0>(a0);
        af[1] = ds128<2048>(a0);
        af[2] = ds128<4096>(a0);
        af[3] = ds128<6144>(a0);
        bg[0] = ds128<0>(b0);
        bg[1] = ds128<1024>(b0);
        bu[0] = ds128<8192>(b0);
        bu[1] = ds128<9216>(b0);
        LGKM0;
        SB0;

        __builtin_amdgcn_s_setprio(1);
#pragma unroll
        for (int i = 0; i < 4; ++i)
#pragma unroll
            for (int j = 0; j < 2; ++j)
                accg[i][j] = __builtin_amdgcn_mfma_f32_16x16x32_f16(af[i], bg[j], accg[i][j], 0, 0, 0);
#pragma unroll
        for (int i = 0; i < 4; ++i)
#pragma unroll
            for (int j = 0; j < 2; ++j)
                accu[i][j] = __builtin_amdgcn_mfma_f32_16x16x32_f16(af[i], bu[j], accu[i][j], 0, 0, 0);
        __builtin_amdgcn_s_setprio(0);
        SB0;   // pin af re-reads below the clusters that consume the old af

        // reads 9-12: af[0..3] <- M-frags 4-7
        af[0] = ds128<8192>(a0);
        af[1] = ds128<10240>(a0);
        af[2] = ds128<12288>(a0);
        af[3] = ds128<14336>(a0);
        LGKM0;
        SB0;

        __builtin_amdgcn_s_setprio(1);
#pragma unroll
        for (int i = 0; i < 4; ++i)
#pragma unroll
            for (int j = 0; j < 2; ++j)
                accg[i + 4][j] = __builtin_amdgcn_mfma_f32_16x16x32_f16(af[i], bg[j], accg[i + 4][j], 0, 0, 0);
#pragma unroll
        for (int i = 0; i < 4; ++i)
#pragma unroll
            for (int j = 0; j < 2; ++j)
                accu[i + 4][j] = __builtin_amdgcn_mfma_f32_16x16x32_f16(af[i], bu[j], accu[i + 4][j], 0, 0, 0);
        __builtin_amdgcn_s_setprio(0);

        cur = nb;
    }

    // ---------- epilogue: h = silu(g) * w * u -> H (f16) ----------
    int cl = lane & 15;
#pragma unroll
    for (int i = 0; i < 8; ++i) {
#pragma unroll
        for (int j = 0; j < 2; ++j) {
            f32x4 gv = accg[i][j];
            f32x4 uv = accu[i][j];
#pragma unroll
            for (int r4 = 0; r4 < 4; ++r4) {
                int r = i * 32 + wr * 16 + q4 * 4 + r4;
                int hr = hrow_s[r];
                if (hr < 0) continue;
                float gg = gv[r4];
                float h = gg / (1.f + __expf(-gg)) * w_s[r] * uv[r4];
                H[(size_t)hr * F_DIM + col0 + (wc * 2 + j) * 16 + cl] = (_Float16)h;
            }
        }
    }
}

// ========== down: 256x128 tile, BK=32, 49KB LDS -> 3 blocks/CU ==========
__global__ __launch_bounds__(512, 6)
void down_kernel(const _Float16* __restrict__ H,
                 const _Float16* __restrict__ Wdh,
                 const int* __restrict__ cnt,
                 const int* __restrict__ rows,
                 float* __restrict__ O) {
    int e = blockIdx.z;
    int c = cnt[e];
    int row0 = blockIdx.y * BM2;
    if (row0 >= c) return;
    int col0 = blockIdx.x * 128;

    __shared__ __align__(16) _Float16 Ab[2][BM2][BKT];   // 32 KB
    __shared__ __align__(16) _Float16 Bb[2][128][BKT];   // 16 KB
    __shared__ int hrow_s[BM2];

    int tid = threadIdx.x;
    int lane = tid & 63;
    int wv = tid >> 6;         // 0..7
    int wr = wv >> 1;          // 0..3 (M quadrant, 64 rows)
    int wc = wv & 1;           // 0..1 (N half, 64 cols)

    if (tid < BM2) {
        int p = row0 + tid;
        hrow_s[tid] = (p < c) ? rows[e * T_TOK + p] : -1;
    }
    __syncthreads();

    int rl = lane >> 2;
    int p4 = lane & 3;
    int lg = p4 ^ ((rl >> 1) & 3);

    // A chunks 2wv, 2wv+1 -> rows 32wv+rl, +16 (slot-gathered H rows)
    int ra0 = wv * 32 + rl;
    int ra1 = ra0 + 16;
    int hA0 = hrow_s[ra0], hA1 = hrow_s[ra1];
    const _Float16* sA0 = H + (size_t)(hA0 >= 0 ? hA0 : 0) * F_DIM + lg * 8;
    const _Float16* sA1 = H + (size_t)(hA1 >= 0 ? hA1 : 0) * F_DIM + lg * 8;
    // B chunk wv -> rows col0 + 16wv + rl
    const _Float16* sB0 = Wdh + ((size_t)e * D_DIM + col0 + wv * 16 + rl) * F_DIM + lg * 8;

    int stOA = wv * 2048;
    int stOB = wv * 1024;

    int m16 = lane & 15, q4 = lane >> 4;
    int cb = ((q4 ^ ((m16 >> 1) & 3)) << 4);
    unsigned Abase = (unsigned)(size_t)(__attribute__((address_space(3))) void*)&Ab[0][0][0]
                     + (unsigned)((wr * 64 + m16) * 64 + cb);
    unsigned Bbase = (unsigned)(size_t)(__attribute__((address_space(3))) void*)&Bb[0][0][0]
                     + (unsigned)((wc * 64 + m16) * 64 + cb);

    // prologue: stage tile 0 into buffer 0
    {
        char* aD = (char*)Ab + stOA;
        char* bD = (char*)Bb + stOB;
        async_lds16(bD,        sB0);
        async_lds16(aD,        sA0);
        async_lds16(aD + 1024, sA1);
    }

    f32x4 acc[4][4];
#pragma unroll
    for (int i = 0; i < 4; ++i)
#pragma unroll
        for (int j = 0; j < 4; ++j) acc[i][j] = (f32x4)0.f;

    int cur = 0;
#pragma unroll 1
    for (int t = 0; t < KTD; ++t) {
        int kn = (t + 1 < KTD) ? (t + 1) * BKT : 0;
        int nb = cur ^ 1;

        VMCNT0;
        __builtin_amdgcn_s_barrier();
        SB0;

        {
            char* aD = (char*)Ab + nb * 16384 + stOA;
            char* bD = (char*)Bb + nb * 8192 + stOB;
            async_lds16(bD,        sB0 + kn);
            async_lds16(aD,        sA0 + kn);
            async_lds16(aD + 1024, sA1 + kn);
        }
        SB0;

        unsigned a0 = Abase + (unsigned)(cur * 16384);
        unsigned b0 = Bbase + (unsigned)(cur * 8192);

        v8h af[4], bf[4];
        af[0] = ds128<0>(a0);
        af[1] = ds128<1024>(a0);
        af[2] = ds128<2048>(a0);
        af[3] = ds128<3072>(a0);
        bf[0] = ds128<0>(b0);
        bf[1] = ds128<1024>(b0);
        bf[2] = ds128<2048>(b0);
        bf[3] = ds128<3072>(b0);
        LGKM0;
        SB0;

        __builtin_amdgcn_s_setprio(1);
#pragma unroll
        for (int i = 0; i < 4; ++i)
#pragma unroll
            for (int j = 0; j < 4; ++j)
                acc[i][j] = __builtin_amdgcn_mfma_f32_16x16x32_f16(af[i], bf[j], acc[i][j], 0, 0, 0);
        __builtin_amdgcn_s_setprio(0);

        cur = nb;
    }

    int cl = lane & 15;
#pragma unroll
    for (int i = 0; i < 4; ++i) {
#pragma unroll
        for (int r4 = 0; r4 < 4; ++r4) {
            int r = wr * 64 + i * 16 + q4 * 4 + r4;
            int hr = hrow_s[r];
            if (hr < 0) continue;
#pragma unroll
            for (int j = 0; j < 4; ++j) {
                int col = col0 + wc * 64 + j * 16 + cl;
                O[(size_t)hr * D_DIM + col] = acc[i][j][r4];
            }
        }
    }
}

// ---------------- combine: out[t] = O[2t] + O[2t+1] ----------------
__global__ void combine_kernel(const float* __restrict__ O, float* __restrict__ out) {
    int t = blockIdx.x;
    int d = threadIdx.x;
    const float4* a = (const float4*)(O + (size_t)(2 * t) * D_DIM);
    const float4* b = (const float4*)(O + (size_t)(2 * t + 1) * D_DIM);
    float4 va = a[d], vb = b[d];
    float4 r; r.x = va.x + vb.x; r.y = va.y + vb.y; r.z = va.z + vb.z; r.w = va.w + vb.w;
    ((float4*)(out + (size_t)t * D_DIM))[d] = r;
}

extern "C" void kernel_launch(void* const* d_in, const int* in_sizes, int n_in,
                              void* d_out, int out_size, void* d_ws, size_t ws_size,
                              hipStream_t stream) {
    const float* x     = (const float*)d_in[0];
    const float* Wgate = (const float*)d_in[1];
    const float* Wg    = (const float*)d_in[2];
    const float* Wu    = (const float*)d_in[3];
    const float* Wd    = (const float*)d_in[4];
    float* out = (float*)d_out;

    char* w = (char*)d_ws;
    int*      cnt  = (int*)w;                          // 32 B, zeroed below
    int*      rows = (int*)(w + 1024);                 // 256 KB
    float*    wts  = (float*)(w + 263168);             // 256 KB
    _Float16* Xh   = (_Float16*)(w + 525312);          // 16 MB

    const size_t OFF_WGH = 17302528;                   // 64 MB f16
    const size_t OFF_WUH = 84411392;
    const size_t OFF_WDH = 151520256;
    const size_t OFF_H   = 218629120;                  // 128 MB
    const size_t OFF_O   = 352846848;                  // 64 MB

    _Float16* Wgh = (_Float16*)(w + OFF_WGH);
    _Float16* Wuh = (_Float16*)(w + OFF_WUH);
    _Float16* Wdh = (_Float16*)(w + OFF_WDH);
    _Float16* H   = (_Float16*)(w + OFF_H);
    float*    O   = (float*)(w + OFF_O);

    hipMemsetAsync(w, 0, 1024, stream);  // zero expert counters

    router_kernel<<<T_TOK, 64, 0, stream>>>(x, Wgate, cnt, rows, wts);
    f32to16_kernel<<<(T_TOK * D_DIM / 4) / 256, 256, 0, stream>>>(x, Xh);

    const int WN4 = (NE * F_DIM * D_DIM / 4);
    f32to16_kernel<<<WN4 / 256, 256, 0, stream>>>(Wg, Wgh);
    f32to16_kernel<<<WN4 / 256, 256, 0, stream>>>(Wu, Wuh);
    f32to16_kernel<<<WN4 / 256, 256, 0, stream>>>(Wd, Wdh);

    gateup_kernel<<<dim3(F_DIM / BN2, T_TOK / BM2, NE), 512, 0, stream>>>(
        Xh, Wgh, Wuh, cnt, rows, wts, H);
    down_kernel<<<dim3(D_DIM / 128, T_TOK / BM2, NE), 512, 0, stream>>>(
        H, Wdh, cnt, rows, O);
    combine_kernel<<<T_TOK, 256, 0, stream>>>(O, out);
}

// Round 6
// 1238.381 us; speedup vs baseline: 3.7184x; 3.7184x over previous
//
#include <hip/hip_runtime.h>
#include <hip/hip_bf16.h>

#define T_TOK 8192
#define D_DIM 1024
#define F_DIM 4096
#define NE 8

// tile geometry (BK=32 -> small LDS -> multi-block/CU)
#define BM2 256
#define BN2 128
#define BKT 32
#define KT2G (D_DIM / BKT)   // 32 gateup K-tiles
#define KTD  (F_DIM / BKT)   // 128 down K-tiles

typedef _Float16 v8h __attribute__((ext_vector_type(8)));
typedef float f32x4 __attribute__((ext_vector_type(4)));

__device__ __forceinline__ void async_lds16(void* lds, const void* g) {
    __builtin_amdgcn_global_load_lds(
        (const __attribute__((address_space(1))) void*)g,
        (__attribute__((address_space(3))) void*)lds,
        16, 0, 0);
}

// opaque LDS read with compile-time offset immediate; no alias info -> no compiler drains.
template<int OFF>
__device__ __forceinline__ v8h ds128(unsigned a) {
    v8h r;
    asm volatile("ds_read_b128 %0, %1 offset:%2" : "=v"(r) : "v"(a), "n"(OFF));
    return r;
}

#define LGKM0 asm volatile("s_waitcnt lgkmcnt(0)" ::: "memory")
#define VMCNT0 asm volatile("s_waitcnt vmcnt(0)" ::: "memory")
#define SB0 __builtin_amdgcn_sched_barrier(0)

// ---------------- router: logits -> top2 -> scatter ----------------
__global__ void router_kernel(const float* __restrict__ x,
                              const float* __restrict__ Wgate,
                              int* __restrict__ cnt,
                              int* __restrict__ rows,
                              float* __restrict__ wts) {
    int t = blockIdx.x;
    int lane = threadIdx.x;
    const float* xr = x + (size_t)t * D_DIM;
    float acc[NE];
#pragma unroll
    for (int e = 0; e < NE; ++e) acc[e] = 0.f;
#pragma unroll
    for (int i = 0; i < D_DIM / 64; ++i) {
        int d = i * 64 + lane;
        float xv = xr[d];
#pragma unroll
        for (int e = 0; e < NE; ++e) acc[e] += xv * Wgate[e * D_DIM + d];
    }
#pragma unroll
    for (int off = 32; off > 0; off >>= 1) {
#pragma unroll
        for (int e = 0; e < NE; ++e) acc[e] += __shfl_xor(acc[e], off, 64);
    }
    if (lane == 0) {
        int e0 = 0;
#pragma unroll
        for (int e = 1; e < NE; ++e) if (acc[e] > acc[e0]) e0 = e;
        int e1 = (e0 == 0) ? 1 : 0;
#pragma unroll
        for (int e = 0; e < NE; ++e) if (e != e0 && acc[e] > acc[e1]) e1 = e;
        float w0 = 1.f / (1.f + __expf(acc[e1] - acc[e0]));
        float w1 = 1.f - w0;
        int p0 = atomicAdd(&cnt[e0], 1);
        rows[e0 * T_TOK + p0] = 2 * t;
        wts[e0 * T_TOK + p0] = w0;
        int p1 = atomicAdd(&cnt[e1], 1);
        rows[e1 * T_TOK + p1] = 2 * t + 1;
        wts[e1 * T_TOK + p1] = w1;
    }
}

// ---------------- generic fp32 -> f16 convert (float4 granules) ----------------
__global__ void f32to16_kernel(const float* __restrict__ src, _Float16* __restrict__ dst) {
    int i = blockIdx.x * blockDim.x + threadIdx.x;
    float4 v = ((const float4*)src)[i];
    union { _Float16 h[4]; uint2 u; } pk;
    pk.h[0] = (_Float16)v.x; pk.h[1] = (_Float16)v.y;
    pk.h[2] = (_Float16)v.z; pk.h[3] = (_Float16)v.w;
    *(uint2*)&dst[(size_t)i * 4] = pk.u;
}

// ========== gateup: 256x128 tile, BK=32, 66KB LDS -> 2 blocks/CU ==========
// r5 post-mortem: __launch_bounds__(512,4) capped VGPR at 64 -> all accumulators spilled
// to scratch (WRITE 6GB, FETCH 4GB, MfmaUtil 1.6%). Reverted to (512,2): compiler used
// 112 VGPR in r4 (no spill); 112 VGPR allows 16 waves/CU, LDS 66KB allows 2 blocks/CU
// -> the intended 2-block TLP regime is now actually reachable.
__global__ __launch_bounds__(512, 2)
void gateup_kernel(const _Float16* __restrict__ Xh,
                   const _Float16* __restrict__ Wgh,
                   const _Float16* __restrict__ Wuh,
                   const int* __restrict__ cnt,
                   const int* __restrict__ rows,
                   const float* __restrict__ wts,
                   _Float16* __restrict__ H) {
    int e = blockIdx.z;
    int c = cnt[e];
    int row0 = blockIdx.y * BM2;
    if (row0 >= c) return;
    int col0 = blockIdx.x * BN2;

    __shared__ __align__(16) _Float16 Ab[2][BM2][BKT];   // 32 KB
    __shared__ __align__(16) _Float16 Bb[2][BM2][BKT];   // 32 KB (gate rows 0-127, up 128-255)
    __shared__ int hrow_s[BM2];
    __shared__ float w_s[BM2];

    int tid = threadIdx.x;
    int lane = tid & 63;
    int wv = tid >> 6;         // 0..7
    int wr = wv >> 2;          // 0..1  (M half: rows wr*16 + i*32)
    int wc = wv & 3;           // 0..3  (N quarter: cols wc*32)

    if (tid < BM2) {
        int p = row0 + tid;
        if (p < c) { hrow_s[tid] = rows[e * T_TOK + p]; w_s[tid] = wts[e * T_TOK + p]; }
        else       { hrow_s[tid] = -1;                  w_s[tid] = 0.f; }
    }
    __syncthreads();

    // ---- staging geometry: chunk = 16 rows x 32 cols (1KB); lane -> row rl, slot p
    int rl = lane >> 2;            // 0..15 row within chunk
    int p4 = lane & 3;             // physical granule slot
    int lg = p4 ^ ((rl >> 1) & 3); // logical granule (involution)

    // A chunks 2wv, 2wv+1 -> rows 32wv+rl, 32wv+16+rl
    int ra0 = wv * 32 + rl;
    int ra1 = ra0 + 16;
    int hA0 = hrow_s[ra0], hA1 = hrow_s[ra1];
    const _Float16* sA0 = Xh + (size_t)(hA0 >= 0 ? (hA0 >> 1) : 0) * D_DIM + lg * 8;
    const _Float16* sA1 = Xh + (size_t)(hA1 >= 0 ? (hA1 >> 1) : 0) * D_DIM + lg * 8;
    // B chunks 2wv, 2wv+1: wv<4 -> Wg rows 32wv+rl(+16); wv>=4 -> Wu rows 32(wv-4)+rl(+16)
    const _Float16* wbase = (wv < 4) ? Wgh : Wuh;
    int rb0 = (wv & 3) * 32 + rl;
    const _Float16* sB0 = wbase + ((size_t)e * F_DIM + col0 + rb0) * D_DIM + lg * 8;
    const _Float16* sB1 = wbase + ((size_t)e * F_DIM + col0 + rb0 + 16) * D_DIM + lg * 8;

    int stO = wv * 2048;   // byte offset of chunk 2wv (wave-uniform; HW adds lane*16)

    // ---- fragment-read constants (swizzled)
    int m16 = lane & 15, q4 = lane >> 4;
    int cb = ((q4 ^ ((m16 >> 1) & 3)) << 4);
    unsigned Abase = (unsigned)(size_t)(__attribute__((address_space(3))) void*)&Ab[0][0][0]
                     + (unsigned)((wr * 16 + m16) * 64 + cb);
    unsigned Bbase = (unsigned)(size_t)(__attribute__((address_space(3))) void*)&Bb[0][0][0]
                     + (unsigned)((wc * 32 + m16) * 64 + cb);

    // ---- prologue: issue stage of tile 0 into buffer 0
    {
        char* aD = (char*)Ab + stO;
        char* bD = (char*)Bb + stO;
        async_lds16(bD,        sB0);
        async_lds16(bD + 1024, sB1);
        async_lds16(aD,        sA0);
        async_lds16(aD + 1024, sA1);
    }

    f32x4 accg[8][2], accu[8][2];
#pragma unroll
    for (int i = 0; i < 8; ++i)
#pragma unroll
        for (int j = 0; j < 2; ++j) { accg[i][j] = (f32x4)0.f; accu[i][j] = (f32x4)0.f; }

    int cur = 0;
#pragma unroll 1
    for (int t = 0; t < KT2G; ++t) {
        int kn = (t + 1 < KT2G) ? (t + 1) * BKT : 0;   // clamped next-tile K offset
        int nb = cur ^ 1;

        VMCNT0;
        __builtin_amdgcn_s_barrier();
        SB0;

        {
            char* aD = (char*)Ab + nb * 16384 + stO;
            char* bD = (char*)Bb + nb * 16384 + stO;
            async_lds16(bD,        sB0 + kn);
            async_lds16(bD + 1024, sB1 + kn);
            async_lds16(aD,        sA0 + kn);
            async_lds16(aD + 1024, sA1 + kn);
        }
        SB0;

        unsigned a0 = Abase + (unsigned)(cur * 16384);
        unsigned b0 = Bbase + (unsigned)(cur * 16384);

        v8h af[4], bg[2], bu[2];

        // reads 1-8: af[0..3] (M-frags 0-3), bg, bu
        af[0] = ds128<0>(a0);
        af[1] = ds128<2048>(a0);
        af[2] = ds128<4096>(a0);
        af[3] = ds128<6144>(a0);
        bg[0] = ds128<0>(b0);
        bg[1] = ds128<1024>(b0);
        bu[0] = ds128<8192>(b0);
        bu[1] = ds128<9216>(b0);
        LGKM0;
        SB0;

        __builtin_amdgcn_s_setprio(1);
#pragma unroll
        for (int i = 0; i < 4; ++i)
#pragma unroll
            for (int j = 0; j < 2; ++j)
                accg[i][j] = __builtin_amdgcn_mfma_f32_16x16x32_f16(af[i], bg[j], accg[i][j], 0, 0, 0);
#pragma unroll
        for (int i = 0; i < 4; ++i)
#pragma unroll
            for (int j = 0; j < 2; ++j)
                accu[i][j] = __builtin_amdgcn_mfma_f32_16x16x32_f16(af[i], bu[j], accu[i][j], 0, 0, 0);
        __builtin_amdgcn_s_setprio(0);
        SB0;   // pin af re-reads below the clusters that consume the old af

        // reads 9-12: af[0..3] <- M-frags 4-7
        af[0] = ds128<8192>(a0);
        af[1] = ds128<10240>(a0);
        af[2] = ds128<12288>(a0);
        af[3] = ds128<14336>(a0);
        LGKM0;
        SB0;

        __builtin_amdgcn_s_setprio(1);
#pragma unroll
        for (int i = 0; i < 4; ++i)
#pragma unroll
            for (int j = 0; j < 2; ++j)
                accg[i + 4][j] = __builtin_amdgcn_mfma_f32_16x16x32_f16(af[i], bg[j], accg[i + 4][j], 0, 0, 0);
#pragma unroll
        for (int i = 0; i < 4; ++i)
#pragma unroll
            for (int j = 0; j < 2; ++j)
                accu[i + 4][j] = __builtin_amdgcn_mfma_f32_16x16x32_f16(af[i], bu[j], accu[i + 4][j], 0, 0, 0);
        __builtin_amdgcn_s_setprio(0);

        cur = nb;
    }

    // ---------- epilogue: h = silu(g) * w * u -> H (f16) ----------
    int cl = lane & 15;
#pragma unroll
    for (int i = 0; i < 8; ++i) {
#pragma unroll
        for (int j = 0; j < 2; ++j) {
            f32x4 gv = accg[i][j];
            f32x4 uv = accu[i][j];
#pragma unroll
            for (int r4 = 0; r4 < 4; ++r4) {
                int r = i * 32 + wr * 16 + q4 * 4 + r4;
                int hr = hrow_s[r];
                if (hr < 0) continue;
                float gg = gv[r4];
                float h = gg / (1.f + __expf(-gg)) * w_s[r] * uv[r4];
                H[(size_t)hr * F_DIM + col0 + (wc * 2 + j) * 16 + cl] = (_Float16)h;
            }
        }
    }
}

// ========== down: 256x128 tile, BK=32, 49KB LDS ==========
__global__ __launch_bounds__(512, 2)
void down_kernel(const _Float16* __restrict__ H,
                 const _Float16* __restrict__ Wdh,
                 const int* __restrict__ cnt,
                 const int* __restrict__ rows,
                 float* __restrict__ O) {
    int e = blockIdx.z;
    int c = cnt[e];
    int row0 = blockIdx.y * BM2;
    if (row0 >= c) return;
    int col0 = blockIdx.x * 128;

    __shared__ __align__(16) _Float16 Ab[2][BM2][BKT];   // 32 KB
    __shared__ __align__(16) _Float16 Bb[2][128][BKT];   // 16 KB
    __shared__ int hrow_s[BM2];

    int tid = threadIdx.x;
    int lane = tid & 63;
    int wv = tid >> 6;         // 0..7
    int wr = wv >> 1;          // 0..3 (M quadrant, 64 rows)
    int wc = wv & 1;           // 0..1 (N half, 64 cols)

    if (tid < BM2) {
        int p = row0 + tid;
        hrow_s[tid] = (p < c) ? rows[e * T_TOK + p] : -1;
    }
    __syncthreads();

    int rl = lane >> 2;
    int p4 = lane & 3;
    int lg = p4 ^ ((rl >> 1) & 3);

    // A chunks 2wv, 2wv+1 -> rows 32wv+rl, +16 (slot-gathered H rows)
    int ra0 = wv * 32 + rl;
    int ra1 = ra0 + 16;
    int hA0 = hrow_s[ra0], hA1 = hrow_s[ra1];
    const _Float16* sA0 = H + (size_t)(hA0 >= 0 ? hA0 : 0) * F_DIM + lg * 8;
    const _Float16* sA1 = H + (size_t)(hA1 >= 0 ? hA1 : 0) * F_DIM + lg * 8;
    // B chunk wv -> rows col0 + 16wv + rl
    const _Float16* sB0 = Wdh + ((size_t)e * D_DIM + col0 + wv * 16 + rl) * F_DIM + lg * 8;

    int stOA = wv * 2048;
    int stOB = wv * 1024;

    int m16 = lane & 15, q4 = lane >> 4;
    int cb = ((q4 ^ ((m16 >> 1) & 3)) << 4);
    unsigned Abase = (unsigned)(size_t)(__attribute__((address_space(3))) void*)&Ab[0][0][0]
                     + (unsigned)((wr * 64 + m16) * 64 + cb);
    unsigned Bbase = (unsigned)(size_t)(__attribute__((address_space(3))) void*)&Bb[0][0][0]
                     + (unsigned)((wc * 64 + m16) * 64 + cb);

    // prologue: stage tile 0 into buffer 0
    {
        char* aD = (char*)Ab + stOA;
        char* bD = (char*)Bb + stOB;
        async_lds16(bD,        sB0);
        async_lds16(aD,        sA0);
        async_lds16(aD + 1024, sA1);
    }

    f32x4 acc[4][4];
#pragma unroll
    for (int i = 0; i < 4; ++i)
#pragma unroll
        for (int j = 0; j < 4; ++j) acc[i][j] = (f32x4)0.f;

    int cur = 0;
#pragma unroll 1
    for (int t = 0; t < KTD; ++t) {
        int kn = (t + 1 < KTD) ? (t + 1) * BKT : 0;
        int nb = cur ^ 1;

        VMCNT0;
        __builtin_amdgcn_s_barrier();
        SB0;

        {
            char* aD = (char*)Ab + nb * 16384 + stOA;
            char* bD = (char*)Bb + nb * 8192 + stOB;
            async_lds16(bD,        sB0 + kn);
            async_lds16(aD,        sA0 + kn);
            async_lds16(aD + 1024, sA1 + kn);
        }
        SB0;

        unsigned a0 = Abase + (unsigned)(cur * 16384);
        unsigned b0 = Bbase + (unsigned)(cur * 8192);

        v8h af[4], bf[4];
        af[0] = ds128<0>(a0);
        af[1] = ds128<1024>(a0);
        af[2] = ds128<2048>(a0);
        af[3] = ds128<3072>(a0);
        bf[0] = ds128<0>(b0);
        bf[1] = ds128<1024>(b0);
        bf[2] = ds128<2048>(b0);
        bf[3] = ds128<3072>(b0);
        LGKM0;
        SB0;

        __builtin_amdgcn_s_setprio(1);
#pragma unroll
        for (int i = 0; i < 4; ++i)
#pragma unroll
            for (int j = 0; j < 4; ++j)
                acc[i][j] = __builtin_amdgcn_mfma_f32_16x16x32_f16(af[i], bf[j], acc[i][j], 0, 0, 0);
        __builtin_amdgcn_s_setprio(0);

        cur = nb;
    }

    int cl = lane & 15;
#pragma unroll
    for (int i = 0; i < 4; ++i) {
#pragma unroll
        for (int r4 = 0; r4 < 4; ++r4) {
            int r = wr * 64 + i * 16 + q4 * 4 + r4;
            int hr = hrow_s[r];
            if (hr < 0) continue;
#pragma unroll
            for (int j = 0; j < 4; ++j) {
                int col = col0 + wc * 64 + j * 16 + cl;
                O[(size_t)hr * D_DIM + col] = acc[i][j][r4];
            }
        }
    }
}

// ---------------- combine: out[t] = O[2t] + O[2t+1] ----------------
__global__ void combine_kernel(const float* __restrict__ O, float* __restrict__ out) {
    int t = blockIdx.x;
    int d = threadIdx.x;
    const float4* a = (const float4*)(O + (size_t)(2 * t) * D_DIM);
    const float4* b = (const float4*)(O + (size_t)(2 * t + 1) * D_DIM);
    float4 va = a[d], vb = b[d];
    float4 r; r.x = va.x + vb.x; r.y = va.y + vb.y; r.z = va.z + vb.z; r.w = va.w + vb.w;
    ((float4*)(out + (size_t)t * D_DIM))[d] = r;
}

extern "C" void kernel_launch(void* const* d_in, const int* in_sizes, int n_in,
                              void* d_out, int out_size, void* d_ws, size_t ws_size,
                              hipStream_t stream) {
    const float* x     = (const float*)d_in[0];
    const float* Wgate = (const float*)d_in[1];
    const float* Wg    = (const float*)d_in[2];
    const float* Wu    = (const float*)d_in[3];
    const float* Wd    = (const float*)d_in[4];
    float* out = (float*)d_out;

    char* w = (char*)d_ws;
    int*      cnt  = (int*)w;                          // 32 B, zeroed below
    int*      rows = (int*)(w + 1024);                 // 256 KB
    float*    wts  = (float*)(w + 263168);             // 256 KB
    _Float16* Xh   = (_Float16*)(w + 525312);          // 16 MB

    const size_t OFF_WGH = 17302528;                   // 64 MB f16
    const size_t OFF_WUH = 84411392;
    const size_t OFF_WDH = 151520256;
    const size_t OFF_H   = 218629120;                  // 128 MB
    const size_t OFF_O   = 352846848;                  // 64 MB

    _Float16* Wgh = (_Float16*)(w + OFF_WGH);
    _Float16* Wuh = (_Float16*)(w + OFF_WUH);
    _Float16* Wdh = (_Float16*)(w + OFF_WDH);
    _Float16* H   = (_Float16*)(w + OFF_H);
    float*    O   = (float*)(w + OFF_O);

    hipMemsetAsync(w, 0, 1024, stream);  // zero expert counters

    router_kernel<<<T_TOK, 64, 0, stream>>>(x, Wgate, cnt, rows, wts);
    f32to16_kernel<<<(T_TOK * D_DIM / 4) / 256, 256, 0, stream>>>(x, Xh);

    const int WN4 = (NE * F_DIM * D_DIM / 4);
    f32to16_kernel<<<WN4 / 256, 256, 0, stream>>>(Wg, Wgh);
    f32to16_kernel<<<WN4 / 256, 256, 0, stream>>>(Wu, Wuh);
    f32to16_kernel<<<WN4 / 256, 256, 0, stream>>>(Wd, Wdh);

    gateup_kernel<<<dim3(F_DIM / BN2, T_TOK / BM2, NE), 512, 0, stream>>>(
        Xh, Wgh, Wuh, cnt, rows, wts, H);
    down_kernel<<<dim3(D_DIM / 128, T_TOK / BM2, NE), 512, 0, stream>>>(
        H, Wdh, cnt, rows, O);
    combine_kernel<<<T_TOK, 256, 0, stream>>>(O, out);
}